// Round 6
// baseline (698.265 us; speedup 1.0000x reference)
//
#include <hip/hip_runtime.h>
#include <stdint.h>

// ---------------------------------------------------------------------------
// SelfAttention B=4, S=2048, E=1024 — ONE plain dispatch, 4 phases separated
// by a software grid barrier (512 blocks, 2/CU co-resident by construction):
//   P0 cvt fp32->bf16 (inputs+weights) + zero rowsum
//   P1 proj: qb = Xq Wq^T, kb = Xk Wk^T, vT = Wv Xv^T   (1536 tile-jobs)
//   P2 scores: Sc = exp(qb kb^T / 32) bf16 + fp32 rowsum atomics (1024 jobs)
//   P3 pv: out = (Sc vT^T) / rowsum                      (512 jobs)
// Barrier: device-scope atomics in d_ws; slots CAS-initialized from the
// harness 0xAA poison before P0 (safe for any arrive ordering).
// GEMM tile: 128x128, BK=64, XOR-swizzled LDS (0 bank conflicts), G2L w=16.
// ---------------------------------------------------------------------------

typedef __attribute__((ext_vector_type(8))) short short8;       // 8 x bf16 frag
typedef __attribute__((ext_vector_type(4))) float floatx4;      // MFMA acc
typedef __attribute__((ext_vector_type(4))) unsigned short u16x4;
typedef __attribute__((ext_vector_type(4))) float f32x4v;

__device__ __forceinline__ unsigned short f32_to_bf16(float f) {
    union { float f; unsigned u; } c; c.f = f;
    unsigned u = c.u;
    return (unsigned short)((u + 0x7fffu + ((u >> 16) & 1u)) >> 16);  // RNE
}

#define BM 128
#define BN 128
#define BK 64
#define NBLK 512
#define POISON 0xAAAAAAAAu

#define G2L(g, l) __builtin_amdgcn_global_load_lds( \
    (__attribute__((address_space(1))) void*)(void*)(g), \
    (__attribute__((address_space(3))) void*)(l), 16, 0, 0)

// software grid barrier: all NBLK blocks co-resident (launch_bounds 256,2 +
// 32KB LDS -> 2 blocks/CU x 256 CU = 512). Release/acquire via __threadfence
// (agent scope -> cross-XCD L2 visibility), arrive via device-scope atomics.
__device__ __forceinline__ void gbar(unsigned* slot) {
    __threadfence();                 // release: drain this thread's stores
    __syncthreads();                 // whole block arrived + stores issued
    if (threadIdx.x == 0) {
        atomicAdd(slot, 1u);
        while (__hip_atomic_load(slot, __ATOMIC_ACQUIRE,
                                 __HIP_MEMORY_SCOPE_AGENT) < NBLK)
            __builtin_amdgcn_s_sleep(2);
        __threadfence();             // acquire
    }
    __syncthreads();
}

// EPI: 0 = store bf16; 1 = store bf16 exp(x*scale) + rowsum atomics;
//      2 = store fp32 x / rowsum[row]
template <int EPI>
__device__ __forceinline__ void gemm_body(
    unsigned short* __restrict__ As, unsigned short* __restrict__ Bs,
    const unsigned short* __restrict__ A, const unsigned short* __restrict__ B,
    void* __restrict__ Cv, int lda, int ldb, int ldc, int K, float scale,
    float* __restrict__ rowsum, int m0, int n0) {
    const int tid  = threadIdx.x;
    const int wave = tid >> 6;
    const int lane = tid & 63;
    const int lm   = lane & 15;   // MFMA row-in-frag
    const int quad = lane >> 4;   // 0..3
    const int wm   = wave >> 1;   // wave tile 2x2
    const int wn   = wave & 1;

    const int srow8 = lane >> 3;                 // row within 8-row group
    const int gcol  = ((lane & 7) ^ srow8) * 8;  // swizzled global col (shorts)

    floatx4 acc[4][4];
#pragma unroll
    for (int i = 0; i < 4; ++i)
#pragma unroll
        for (int j = 0; j < 4; ++j) acc[i][j] = (floatx4)0.0f;

    for (int k0 = 0; k0 < K; k0 += BK) {
#pragma unroll
        for (int i = 0; i < 4; ++i) {
            const int rbase = wave * 32 + i * 8;
            G2L(A + (size_t)(m0 + rbase + srow8) * lda + k0 + gcol,
                &As[rbase * BK]);
            G2L(B + (size_t)(n0 + rbase + srow8) * ldb + k0 + gcol,
                &Bs[rbase * BK]);
        }
        __syncthreads();

#pragma unroll
        for (int s = 0; s < 2; ++s) {
            short8 af[4], bf[4];
#pragma unroll
            for (int t = 0; t < 4; ++t) {
                const int cs = ((s * 4 + quad) ^ (lm & 7)) * 8;
                af[t] = *(const short8*)&As[(wm * 64 + t * 16 + lm) * BK + cs];
                bf[t] = *(const short8*)&Bs[(wn * 64 + t * 16 + lm) * BK + cs];
            }
#pragma unroll
            for (int mt = 0; mt < 4; ++mt)
#pragma unroll
                for (int nt = 0; nt < 4; ++nt)
                    acc[mt][nt] = __builtin_amdgcn_mfma_f32_16x16x32_bf16(
                        af[mt], bf[nt], acc[mt][nt], 0, 0, 0);
        }
        __syncthreads();
    }

    // epilogue: D row = quad*4 + reg, col = lane&15 (m89/m91 mapping)
    if constexpr (EPI == 0) {
        unsigned short* C = (unsigned short*)Cv;
#pragma unroll
        for (int mt = 0; mt < 4; ++mt)
#pragma unroll
            for (int nt = 0; nt < 4; ++nt)
#pragma unroll
                for (int r = 0; r < 4; ++r) {
                    const int row = m0 + wm * 64 + mt * 16 + quad * 4 + r;
                    const int col = n0 + wn * 64 + nt * 16 + lm;
                    C[(size_t)row * ldc + col] = f32_to_bf16(acc[mt][nt][r]);
                }
    } else if constexpr (EPI == 1) {
        unsigned short* C = (unsigned short*)Cv;
        float psum[4][4];
#pragma unroll
        for (int mt = 0; mt < 4; ++mt)
#pragma unroll
            for (int r = 0; r < 4; ++r) psum[mt][r] = 0.0f;
#pragma unroll
        for (int mt = 0; mt < 4; ++mt)
#pragma unroll
            for (int nt = 0; nt < 4; ++nt)
#pragma unroll
                for (int r = 0; r < 4; ++r) {
                    const int row = m0 + wm * 64 + mt * 16 + quad * 4 + r;
                    const int col = n0 + wn * 64 + nt * 16 + lm;
                    const float p = __expf(acc[mt][nt][r] * scale);
                    psum[mt][r] += p;
                    C[(size_t)row * ldc + col] = f32_to_bf16(p);
                }
#pragma unroll
        for (int off = 1; off <= 8; off <<= 1)
#pragma unroll
            for (int mt = 0; mt < 4; ++mt)
#pragma unroll
                for (int r = 0; r < 4; ++r)
                    psum[mt][r] += __shfl_xor(psum[mt][r], off);
        if (lm == 0) {
#pragma unroll
            for (int mt = 0; mt < 4; ++mt)
#pragma unroll
                for (int r = 0; r < 4; ++r)
                    atomicAdd(&rowsum[m0 + wm * 64 + mt * 16 + quad * 4 + r],
                              psum[mt][r]);
        }
    } else {
        float* C = (float*)Cv;
#pragma unroll
        for (int mt = 0; mt < 4; ++mt)
#pragma unroll
            for (int r = 0; r < 4; ++r) {
                const int row = m0 + wm * 64 + mt * 16 + quad * 4 + r;
                const float inv = 1.0f / rowsum[row];
#pragma unroll
                for (int nt = 0; nt < 4; ++nt) {
                    const int col = n0 + wn * 64 + nt * 16 + lm;
                    C[(size_t)row * ldc + col] = acc[mt][nt][r] * inv;
                }
            }
    }
}

__global__ __launch_bounds__(256, 2) void attn_all(
    const float* __restrict__ q_in, const float* __restrict__ k_in,
    const float* __restrict__ v_in, const float* __restrict__ wq_in,
    const float* __restrict__ wk_in, const float* __restrict__ wv_in,
    unsigned short* __restrict__ Xq, unsigned short* __restrict__ Xk,
    unsigned short* __restrict__ Xv, unsigned short* __restrict__ Wq,
    unsigned short* __restrict__ Wk, unsigned short* __restrict__ Wv,
    unsigned short* __restrict__ qb, unsigned short* __restrict__ kb,
    unsigned short* __restrict__ vT, unsigned short* __restrict__ Sc,
    float* __restrict__ rowsum, unsigned* __restrict__ bslots,
    float* __restrict__ out) {
    __shared__ unsigned short As[BM * BK];
    __shared__ unsigned short Bs[BN * BK];
    const int b = blockIdx.x;

    // barrier-slot init from harness poison, BEFORE any arrive can happen.
    // Idempotent: exactly one CAS flips poison->0; safe if already 0.
    if (threadIdx.x < 3) atomicCAS(&bslots[threadIdx.x], POISON, 0u);

    // ---- P0: converts + rowsum zero -------------------------------------
    {
        const long NTE4 = 2097152;  // 8192*1024/4
        const long NW4  = 262144;   // 1024*1024/4
        const long G = 3 * NTE4 + 3 * NW4 + 2048;
        for (long i0 = (long)b * 256 + threadIdx.x; i0 < G;
             i0 += (long)NBLK * 256) {
            long i = i0, j;
            const float* src; unsigned short* dst;
            if (i < 3 * NTE4) {
                int a = (int)(i / NTE4); j = i - (long)a * NTE4;
                src = a == 0 ? q_in : a == 1 ? k_in : v_in;
                dst = a == 0 ? Xq : a == 1 ? Xk : Xv;
            } else {
                i -= 3 * NTE4;
                if (i < 3 * NW4) {
                    int a = (int)(i / NW4); j = i - (long)a * NW4;
                    src = a == 0 ? wq_in : a == 1 ? wk_in : wv_in;
                    dst = a == 0 ? Wq : a == 1 ? Wk : Wv;
                } else {
                    ((f32x4v*)rowsum)[i - 3 * NW4] = (f32x4v)0.0f;
                    continue;
                }
            }
            f32x4v f = ((const f32x4v*)src)[j];
            u16x4 o;
#pragma unroll
            for (int t = 0; t < 4; ++t) o[t] = f32_to_bf16(f[t]);
            ((u16x4*)dst)[j] = o;
        }
    }
    gbar(&bslots[0]);

    // ---- P1: projections, 3 rounds x 512 blocks = 1536 tile-jobs --------
    for (int r = 0; r < 3; ++r) {
        const unsigned short *A_, *B_;
        unsigned short* C_;
        int ldc_, m0, n0;
        if (r == 0)      { A_ = Xq; B_ = Wq; C_ = qb; }
        else if (r == 1) { A_ = Xk; B_ = Wk; C_ = kb; }
        else             { A_ = Wv; B_ = Xv; C_ = vT; }
        if (r < 2) { m0 = (b & 63) * BM; n0 = (b >> 6) * BN; ldc_ = 1024; }
        else       { m0 = (b >> 6) * BM; n0 = (b & 63) * BN; ldc_ = 8192; }
        gemm_body<0>(As, Bs, A_, B_, C_, 1024, 1024, ldc_, 1024,
                     1.0f, nullptr, m0, n0);
    }
    gbar(&bslots[1]);

    // ---- P2: scores, 2 rounds x 512 = 1024 jobs (4 batches x 16x16) -----
    for (int r = 0; r < 2; ++r) {
        const int z = (r << 1) | (b >> 8);
        const int rem = b & 255;
        const int m0 = (rem & 15) * BM, n0 = (rem >> 4) * BN;
        gemm_body<1>(As, Bs, qb + (long)z * 2048 * 1024,
                     kb + (long)z * 2048 * 1024, Sc + (long)z * 2048 * 2048,
                     1024, 1024, 2048, 1024, 1.0f / 32.0f,
                     rowsum + z * 2048, m0, n0);
    }
    gbar(&bslots[2]);

    // ---- P3: pv, 512 jobs (4 batches x 16x8) ----------------------------
    {
        const int z = b >> 7, rem = b & 127;
        const int m0 = (rem & 15) * BM, n0 = (rem >> 4) * BN;
        gemm_body<2>(As, Bs, Sc + (long)z * 2048 * 2048, vT + (long)z * 2048,
                     out + (long)z * 2048 * 1024, 2048, 8192, 1024, 2048,
                     1.0f, rowsum + z * 2048, m0, n0);
    }
}

// ---------------------------------------------------------------------------
extern "C" void kernel_launch(void* const* d_in, const int* in_sizes, int n_in,
                              void* d_out, int out_size, void* d_ws, size_t ws_size,
                              hipStream_t stream) {
    const float* q_in = (const float*)d_in[0];
    const float* k_in = (const float*)d_in[1];
    const float* v_in = (const float*)d_in[2];
    const float* Qw_f = (const float*)d_in[3];
    const float* Kw_f = (const float*)d_in[4];
    const float* Vw_f = (const float*)d_in[5];
    float* out = (float*)d_out;

    const int Bb = 4, S = 2048, E = 1024;
    const size_t TOK = (size_t)Bb * S;       // 8192
    const size_t NTE = TOK * E;              // 8,388,608
    const size_t NW  = (size_t)E * E;        // 1,048,576

    unsigned short* ws = (unsigned short*)d_ws;
    unsigned short* Xq = ws;            // [8192,1024]
    unsigned short* Xk = Xq + NTE;
    unsigned short* Xv = Xk + NTE;
    unsigned short* Wq = Xv + NTE;      // [1024,1024]
    unsigned short* Wk = Wq + NW;
    unsigned short* Wv = Wk + NW;
    unsigned short* qb = Wv + NW;       // [8192,1024]
    unsigned short* kb = qb + NTE;
    unsigned short* vT = kb + NTE;      // [1024 e][8192 tok]
    unsigned short* Sc = vT + NTE;      // [4][2048][2048] exp-scores
    float* rowsum = (float*)(Sc + (size_t)Bb * S * S);  // [4][2048]
    unsigned* bslots = (unsigned*)(rowsum + Bb * S);    // 3 barrier slots

    attn_all<<<dim3(NBLK), dim3(256), 0, stream>>>(
        q_in, k_in, v_in, Qw_f, Kw_f, Vw_f,
        Xq, Xk, Xv, Wq, Wk, Wv,
        qb, kb, vT, Sc, rowsum, bslots, out);
}

// Round 7
// 487.433 us; speedup vs baseline: 1.4325x; 1.4325x over previous
//
#include <hip/hip_runtime.h>
#include <stdint.h>

// ---------------------------------------------------------------------------
// SelfAttention B=4, S=2048, E=1024 — ONE plain dispatch, 4 phases separated
// by a software grid barrier (512 blocks, 2/CU co-resident by construction):
//   P0 cvt fp32->bf16 (inputs+weights) + zero rowsum
//   P1 proj: qb = Xq Wq^T, kb = Xk Wk^T, vT = Wv Xv^T   (1536 tile-jobs)
//   P2 scores: Sc = exp(qb kb^T / 32) bf16 + fp32 rowsum atomics (1024 jobs)
//   P3 pv: out = (Sc vT^T) / rowsum                      (512 jobs)
// Barrier: RELAXED spin + single acquire fence on exit. R6's bug: acquire
// atomic-load in the spin loop emits buffer_inv (L1+L2 invalidate) per
// iteration on gfx950 -> spinners poisoned co-resident workers' L2
// (MfmaUtil 8%, FETCH +40%). Relaxed load bypasses L1 but doesn't invalidate.
// GEMM tile: 128x128, BK=64, XOR-swizzled LDS (0 bank conflicts), G2L w=16.
// ---------------------------------------------------------------------------

typedef __attribute__((ext_vector_type(8))) short short8;       // 8 x bf16 frag
typedef __attribute__((ext_vector_type(4))) float floatx4;      // MFMA acc
typedef __attribute__((ext_vector_type(4))) unsigned short u16x4;
typedef __attribute__((ext_vector_type(4))) float f32x4v;

__device__ __forceinline__ unsigned short f32_to_bf16(float f) {
    union { float f; unsigned u; } c; c.f = f;
    unsigned u = c.u;
    return (unsigned short)((u + 0x7fffu + ((u >> 16) & 1u)) >> 16);  // RNE
}

#define BM 128
#define BN 128
#define BK 64
#define NBLK 512
#define POISON 0xAAAAAAAAu

#define G2L(g, l) __builtin_amdgcn_global_load_lds( \
    (__attribute__((address_space(1))) void*)(void*)(g), \
    (__attribute__((address_space(3))) void*)(l), 16, 0, 0)

// software grid barrier. All NBLK blocks co-resident (2 blocks/CU x 256 CU).
// Release: syncthreads (block stores drained) -> thread0 fence (wb this
// XCD's L2) -> relaxed arrive. Spin: RELAXED agent load (no buffer_inv!).
// Acquire: ONE fence after spin exit.
__device__ __forceinline__ void gbar(unsigned* slot) {
    __syncthreads();                 // block arrived; stores drained (vmcnt 0)
    if (threadIdx.x == 0) {
        __threadfence();             // release: write back this XCD's L2
        atomicAdd(slot, 1u);         // arrive
        while (__hip_atomic_load(slot, __ATOMIC_RELAXED,
                                 __HIP_MEMORY_SCOPE_AGENT) < NBLK)
            __builtin_amdgcn_s_sleep(8);
        __threadfence();             // acquire: invalidate stale caches ONCE
    }
    __syncthreads();
}

// EPI: 0 = store bf16; 1 = store bf16 exp(x*scale) + rowsum atomics;
//      2 = store fp32 x / rowsum[row]
template <int EPI>
__device__ __forceinline__ void gemm_body(
    unsigned short* __restrict__ As, unsigned short* __restrict__ Bs,
    const unsigned short* __restrict__ A, const unsigned short* __restrict__ B,
    void* __restrict__ Cv, int lda, int ldb, int ldc, int K, float scale,
    float* __restrict__ rowsum, int m0, int n0) {
    const int tid  = threadIdx.x;
    const int wave = tid >> 6;
    const int lane = tid & 63;
    const int lm   = lane & 15;   // MFMA row-in-frag
    const int quad = lane >> 4;   // 0..3
    const int wm   = wave >> 1;   // wave tile 2x2
    const int wn   = wave & 1;

    const int srow8 = lane >> 3;                 // row within 8-row group
    const int gcol  = ((lane & 7) ^ srow8) * 8;  // swizzled global col (shorts)

    floatx4 acc[4][4];
#pragma unroll
    for (int i = 0; i < 4; ++i)
#pragma unroll
        for (int j = 0; j < 4; ++j) acc[i][j] = (floatx4)0.0f;

    for (int k0 = 0; k0 < K; k0 += BK) {
#pragma unroll
        for (int i = 0; i < 4; ++i) {
            const int rbase = wave * 32 + i * 8;
            G2L(A + (size_t)(m0 + rbase + srow8) * lda + k0 + gcol,
                &As[rbase * BK]);
            G2L(B + (size_t)(n0 + rbase + srow8) * ldb + k0 + gcol,
                &Bs[rbase * BK]);
        }
        __syncthreads();

#pragma unroll
        for (int s = 0; s < 2; ++s) {
            short8 af[4], bf[4];
#pragma unroll
            for (int t = 0; t < 4; ++t) {
                const int cs = ((s * 4 + quad) ^ (lm & 7)) * 8;
                af[t] = *(const short8*)&As[(wm * 64 + t * 16 + lm) * BK + cs];
                bf[t] = *(const short8*)&Bs[(wn * 64 + t * 16 + lm) * BK + cs];
            }
#pragma unroll
            for (int mt = 0; mt < 4; ++mt)
#pragma unroll
                for (int nt = 0; nt < 4; ++nt)
                    acc[mt][nt] = __builtin_amdgcn_mfma_f32_16x16x32_bf16(
                        af[mt], bf[nt], acc[mt][nt], 0, 0, 0);
        }
        __syncthreads();
    }

    // epilogue: D row = quad*4 + reg, col = lane&15 (m89/m91 mapping)
    if constexpr (EPI == 0) {
        unsigned short* C = (unsigned short*)Cv;
#pragma unroll
        for (int mt = 0; mt < 4; ++mt)
#pragma unroll
            for (int nt = 0; nt < 4; ++nt)
#pragma unroll
                for (int r = 0; r < 4; ++r) {
                    const int row = m0 + wm * 64 + mt * 16 + quad * 4 + r;
                    const int col = n0 + wn * 64 + nt * 16 + lm;
                    C[(size_t)row * ldc + col] = f32_to_bf16(acc[mt][nt][r]);
                }
    } else if constexpr (EPI == 1) {
        unsigned short* C = (unsigned short*)Cv;
        float psum[4][4];
#pragma unroll
        for (int mt = 0; mt < 4; ++mt)
#pragma unroll
            for (int r = 0; r < 4; ++r) psum[mt][r] = 0.0f;
#pragma unroll
        for (int mt = 0; mt < 4; ++mt)
#pragma unroll
            for (int nt = 0; nt < 4; ++nt)
#pragma unroll
                for (int r = 0; r < 4; ++r) {
                    const int row = m0 + wm * 64 + mt * 16 + quad * 4 + r;
                    const int col = n0 + wn * 64 + nt * 16 + lm;
                    const float p = __expf(acc[mt][nt][r] * scale);
                    psum[mt][r] += p;
                    C[(size_t)row * ldc + col] = f32_to_bf16(p);
                }
#pragma unroll
        for (int off = 1; off <= 8; off <<= 1)
#pragma unroll
            for (int mt = 0; mt < 4; ++mt)
#pragma unroll
                for (int r = 0; r < 4; ++r)
                    psum[mt][r] += __shfl_xor(psum[mt][r], off);
        if (lm == 0) {
#pragma unroll
            for (int mt = 0; mt < 4; ++mt)
#pragma unroll
                for (int r = 0; r < 4; ++r)
                    atomicAdd(&rowsum[m0 + wm * 64 + mt * 16 + quad * 4 + r],
                              psum[mt][r]);
        }
    } else {
        float* C = (float*)Cv;
#pragma unroll
        for (int mt = 0; mt < 4; ++mt)
#pragma unroll
            for (int r = 0; r < 4; ++r) {
                const int row = m0 + wm * 64 + mt * 16 + quad * 4 + r;
                const float inv = 1.0f / rowsum[row];
#pragma unroll
                for (int nt = 0; nt < 4; ++nt) {
                    const int col = n0 + wn * 64 + nt * 16 + lm;
                    C[(size_t)row * ldc + col] = acc[mt][nt][r] * inv;
                }
            }
    }
}

__global__ __launch_bounds__(256, 2) void attn_all(
    const float* __restrict__ q_in, const float* __restrict__ k_in,
    const float* __restrict__ v_in, const float* __restrict__ wq_in,
    const float* __restrict__ wk_in, const float* __restrict__ wv_in,
    unsigned short* __restrict__ Xq, unsigned short* __restrict__ Xk,
    unsigned short* __restrict__ Xv, unsigned short* __restrict__ Wq,
    unsigned short* __restrict__ Wk, unsigned short* __restrict__ Wv,
    unsigned short* __restrict__ qb, unsigned short* __restrict__ kb,
    unsigned short* __restrict__ vT, unsigned short* __restrict__ Sc,
    float* __restrict__ rowsum, unsigned* __restrict__ bslots,
    float* __restrict__ out) {
    __shared__ unsigned short As[BM * BK];
    __shared__ unsigned short Bs[BN * BK];
    const int b = blockIdx.x;

    // barrier-slot init from harness poison, BEFORE any arrive can happen
    // (all blocks co-resident; first arrive is ~P0-duration after start).
    if (threadIdx.x < 3) atomicCAS(&bslots[threadIdx.x], POISON, 0u);

    // ---- P0: converts + rowsum zero -------------------------------------
    {
        const long NTE4 = 2097152;  // 8192*1024/4
        const long NW4  = 262144;   // 1024*1024/4
        const long G = 3 * NTE4 + 3 * NW4 + 2048;
        for (long i0 = (long)b * 256 + threadIdx.x; i0 < G;
             i0 += (long)NBLK * 256) {
            long i = i0, j;
            const float* src; unsigned short* dst;
            if (i < 3 * NTE4) {
                int a = (int)(i / NTE4); j = i - (long)a * NTE4;
                src = a == 0 ? q_in : a == 1 ? k_in : v_in;
                dst = a == 0 ? Xq : a == 1 ? Xk : Xv;
            } else {
                i -= 3 * NTE4;
                if (i < 3 * NW4) {
                    int a = (int)(i / NW4); j = i - (long)a * NW4;
                    src = a == 0 ? wq_in : a == 1 ? wk_in : wv_in;
                    dst = a == 0 ? Wq : a == 1 ? Wk : Wv;
                } else {
                    ((f32x4v*)rowsum)[i - 3 * NW4] = (f32x4v)0.0f;
                    continue;
                }
            }
            f32x4v f = ((const f32x4v*)src)[j];
            u16x4 o;
#pragma unroll
            for (int t = 0; t < 4; ++t) o[t] = f32_to_bf16(f[t]);
            ((u16x4*)dst)[j] = o;
        }
    }
    gbar(&bslots[0]);

    // ---- P1: projections, 3 rounds x 512 blocks = 1536 tile-jobs --------
    for (int r = 0; r < 3; ++r) {
        const unsigned short *A_, *B_;
        unsigned short* C_;
        int ldc_, m0, n0;
        if (r == 0)      { A_ = Xq; B_ = Wq; C_ = qb; }
        else if (r == 1) { A_ = Xk; B_ = Wk; C_ = kb; }
        else             { A_ = Wv; B_ = Xv; C_ = vT; }
        if (r < 2) { m0 = (b & 63) * BM; n0 = (b >> 6) * BN; ldc_ = 1024; }
        else       { m0 = (b >> 6) * BM; n0 = (b & 63) * BN; ldc_ = 8192; }
        gemm_body<0>(As, Bs, A_, B_, C_, 1024, 1024, ldc_, 1024,
                     1.0f, nullptr, m0, n0);
    }
    gbar(&bslots[1]);

    // ---- P2: scores, 2 rounds x 512 = 1024 jobs (4 batches x 16x16) -----
    for (int r = 0; r < 2; ++r) {
        const int z = (r << 1) | (b >> 8);
        const int rem = b & 255;
        const int m0 = (rem & 15) * BM, n0 = (rem >> 4) * BN;
        gemm_body<1>(As, Bs, qb + (long)z * 2048 * 1024,
                     kb + (long)z * 2048 * 1024, Sc + (long)z * 2048 * 2048,
                     1024, 1024, 2048, 1024, 1.0f / 32.0f,
                     rowsum + z * 2048, m0, n0);
    }
    gbar(&bslots[2]);

    // ---- P3: pv, 512 jobs (4 batches x 16x8) ----------------------------
    {
        const int z = b >> 7, rem = b & 127;
        const int m0 = (rem & 15) * BM, n0 = (rem >> 4) * BN;
        gemm_body<2>(As, Bs, Sc + (long)z * 2048 * 2048, vT + (long)z * 2048,
                     out + (long)z * 2048 * 1024, 2048, 8192, 1024, 2048,
                     1.0f, rowsum + z * 2048, m0, n0);
    }
}

// ---------------------------------------------------------------------------
extern "C" void kernel_launch(void* const* d_in, const int* in_sizes, int n_in,
                              void* d_out, int out_size, void* d_ws, size_t ws_size,
                              hipStream_t stream) {
    const float* q_in = (const float*)d_in[0];
    const float* k_in = (const float*)d_in[1];
    const float* v_in = (const float*)d_in[2];
    const float* Qw_f = (const float*)d_in[3];
    const float* Kw_f = (const float*)d_in[4];
    const float* Vw_f = (const float*)d_in[5];
    float* out = (float*)d_out;

    const int Bb = 4, S = 2048, E = 1024;
    const size_t TOK = (size_t)Bb * S;       // 8192
    const size_t NTE = TOK * E;              // 8,388,608
    const size_t NW  = (size_t)E * E;        // 1,048,576

    unsigned short* ws = (unsigned short*)d_ws;
    unsigned short* Xq = ws;            // [8192,1024]
    unsigned short* Xk = Xq + NTE;
    unsigned short* Xv = Xk + NTE;
    unsigned short* Wq = Xv + NTE;      // [1024,1024]
    unsigned short* Wk = Wq + NW;
    unsigned short* Wv = Wk + NW;
    unsigned short* qb = Wv + NW;       // [8192,1024]
    unsigned short* kb = qb + NTE;
    unsigned short* vT = kb + NTE;      // [1024 e][8192 tok]
    unsigned short* Sc = vT + NTE;      // [4][2048][2048] exp-scores
    float* rowsum = (float*)(Sc + (size_t)Bb * S * S);  // [4][2048]
    unsigned* bslots = (unsigned*)(rowsum + Bb * S);    // 3 barrier slots

    attn_all<<<dim3(NBLK), dim3(256), 0, stream>>>(
        q_in, k_in, v_in, Qw_f, Kw_f, Vw_f,
        Xq, Xk, Xv, Wq, Wk, Wv,
        qb, kb, vT, Sc, rowsum, bslots, out);
}

// Round 8
// 274.818 us; speedup vs baseline: 2.5408x; 1.7737x over previous
//
#include <hip/hip_runtime.h>
#include <stdint.h>

// ---------------------------------------------------------------------------
// SelfAttention: B=4, S=2048, E=1024 (single head)  — R4 structure (proven)
//   q = Xq @ Wq^T ; k = Xk @ Wk^T ; vT = Wv @ Xv^T     (merged: 1 dispatch)
//   P = exp(q k^T / 32)  (fp32-safe, no max-sub; rowsums via epilogue atomics)
//   out = (P @ v) / rowsum
// bf16 MFMA GEMMs, BK=64, XOR-swizzled LDS (0 conflicts), G2L width-16.
// R8 change: __launch_bounds__(256,4) -> 4 blocks/CU co-resident (was 2).
// VGPR 64 and 32KB LDS both permit it; extra blocks hide the per-block
// global_load_lds -> syncthreads drain (R4: MfmaUtil 39%, VALU 23%, HBM 22%,
// occupancy 30% -- latency-bound, every pipe idle).
// ---------------------------------------------------------------------------

typedef __attribute__((ext_vector_type(8))) short short8;       // 8 x bf16 frag
typedef __attribute__((ext_vector_type(4))) float floatx4;      // MFMA acc
typedef __attribute__((ext_vector_type(4))) unsigned short u16x4;
typedef __attribute__((ext_vector_type(4))) float f32x4v;

__device__ __forceinline__ unsigned short f32_to_bf16(float f) {
    union { float f; unsigned u; } c; c.f = f;
    unsigned u = c.u;
    return (unsigned short)((u + 0x7fffu + ((u >> 16) & 1u)) >> 16);  // RNE
}

// ---- merged fp32->bf16 converts (3x input, 3x weight) + rowsum zero ------
__global__ __launch_bounds__(256) void cvt_all(
    const float* __restrict__ q, const float* __restrict__ k,
    const float* __restrict__ v, const float* __restrict__ wq,
    const float* __restrict__ wk, const float* __restrict__ wv,
    unsigned short* __restrict__ Xq, unsigned short* __restrict__ Xk,
    unsigned short* __restrict__ Xv, unsigned short* __restrict__ Wq,
    unsigned short* __restrict__ Wk, unsigned short* __restrict__ Wv,
    float* __restrict__ rowsum) {
    const long NTE4 = 2097152;  // 8192*1024/4
    const long NW4  = 262144;   // 1024*1024/4
    long i = (long)blockIdx.x * 256 + threadIdx.x;
    const float* src;
    unsigned short* dst;
    long j;
    if (i < 3 * NTE4) {
        int a = (int)(i / NTE4); j = i - (long)a * NTE4;
        src = a == 0 ? q : a == 1 ? k : v;
        dst = a == 0 ? Xq : a == 1 ? Xk : Xv;
    } else {
        i -= 3 * NTE4;
        if (i < 3 * NW4) {
            int a = (int)(i / NW4); j = i - (long)a * NW4;
            src = a == 0 ? wq : a == 1 ? wk : wv;
            dst = a == 0 ? Wq : a == 1 ? Wk : Wv;
        } else {
            i -= 3 * NW4;           // 2048 groups -> rowsum[0..8191] = 0
            ((f32x4v*)rowsum)[i] = (f32x4v)0.0f;
            return;
        }
    }
    f32x4v f = ((const f32x4v*)src)[j];
    u16x4 o;
#pragma unroll
    for (int t = 0; t < 4; ++t) o[t] = f32_to_bf16(f[t]);
    ((u16x4*)dst)[j] = o;
}

// ---- NT GEMM body: C[m][n] = f(scale * sum_k A[m][k] * B[n][k]) ----------
// 128x128 tile, BK=64, 4 waves (2x2), 2 k-steps x 4x4 MFMA 16x16x32 per wave.
#define BM 128
#define BN 128
#define BK 64

#define G2L(g, l) __builtin_amdgcn_global_load_lds( \
    (__attribute__((address_space(1))) void*)(void*)(g), \
    (__attribute__((address_space(3))) void*)(l), 16, 0, 0)

// EPI: 0 = store bf16; 1 = store bf16 exp(x*scale) + rowsum atomics;
//      2 = store fp32 x / rowsum[row]
template <int EPI>
__device__ __forceinline__ void gemm_body(
    const unsigned short* __restrict__ A, const unsigned short* __restrict__ B,
    void* __restrict__ Cv, int lda, int ldb, int ldc, int K, float scale,
    float* __restrict__ rowsum, int m0, int n0) {
    __shared__ unsigned short As[BM * BK];
    __shared__ unsigned short Bs[BN * BK];

    const int tid  = threadIdx.x;
    const int wave = tid >> 6;
    const int lane = tid & 63;
    const int lm   = lane & 15;   // MFMA row-in-frag
    const int quad = lane >> 4;   // 0..3
    const int wm   = wave >> 1;   // wave tile 2x2
    const int wn   = wave & 1;

    const int srow8 = lane >> 3;                 // row within 8-row group
    const int gcol  = ((lane & 7) ^ srow8) * 8;  // swizzled global col (shorts)

    floatx4 acc[4][4];
#pragma unroll
    for (int i = 0; i < 4; ++i)
#pragma unroll
        for (int j = 0; j < 4; ++j) acc[i][j] = (floatx4)0.0f;

    for (int k0 = 0; k0 < K; k0 += BK) {
#pragma unroll
        for (int i = 0; i < 4; ++i) {
            const int rbase = wave * 32 + i * 8;
            G2L(A + (size_t)(m0 + rbase + srow8) * lda + k0 + gcol,
                &As[rbase * BK]);
            G2L(B + (size_t)(n0 + rbase + srow8) * ldb + k0 + gcol,
                &Bs[rbase * BK]);
        }
        __syncthreads();

#pragma unroll
        for (int s = 0; s < 2; ++s) {
            short8 af[4], bf[4];
#pragma unroll
            for (int t = 0; t < 4; ++t) {
                const int cs = ((s * 4 + quad) ^ (lm & 7)) * 8;
                af[t] = *(const short8*)&As[(wm * 64 + t * 16 + lm) * BK + cs];
                bf[t] = *(const short8*)&Bs[(wn * 64 + t * 16 + lm) * BK + cs];
            }
#pragma unroll
            for (int mt = 0; mt < 4; ++mt)
#pragma unroll
                for (int nt = 0; nt < 4; ++nt)
                    acc[mt][nt] = __builtin_amdgcn_mfma_f32_16x16x32_bf16(
                        af[mt], bf[nt], acc[mt][nt], 0, 0, 0);
        }
        __syncthreads();
    }

    // epilogue: D row = quad*4 + reg, col = lane&15 (m89/m91 mapping)
    if constexpr (EPI == 0) {
        unsigned short* C = (unsigned short*)Cv;
#pragma unroll
        for (int mt = 0; mt < 4; ++mt)
#pragma unroll
            for (int nt = 0; nt < 4; ++nt)
#pragma unroll
                for (int r = 0; r < 4; ++r) {
                    const int row = m0 + wm * 64 + mt * 16 + quad * 4 + r;
                    const int col = n0 + wn * 64 + nt * 16 + lm;
                    C[(size_t)row * ldc + col] = f32_to_bf16(acc[mt][nt][r]);
                }
    } else if constexpr (EPI == 1) {
        unsigned short* C = (unsigned short*)Cv;
        float psum[4][4];
#pragma unroll
        for (int mt = 0; mt < 4; ++mt)
#pragma unroll
            for (int r = 0; r < 4; ++r) psum[mt][r] = 0.0f;
#pragma unroll
        for (int mt = 0; mt < 4; ++mt)
#pragma unroll
            for (int nt = 0; nt < 4; ++nt)
#pragma unroll
                for (int r = 0; r < 4; ++r) {
                    const int row = m0 + wm * 64 + mt * 16 + quad * 4 + r;
                    const int col = n0 + wn * 64 + nt * 16 + lm;
                    const float p = __expf(acc[mt][nt][r] * scale);
                    psum[mt][r] += p;
                    C[(size_t)row * ldc + col] = f32_to_bf16(p);
                }
#pragma unroll
        for (int off = 1; off <= 8; off <<= 1)
#pragma unroll
            for (int mt = 0; mt < 4; ++mt)
#pragma unroll
                for (int r = 0; r < 4; ++r)
                    psum[mt][r] += __shfl_xor(psum[mt][r], off);
        if (lm == 0) {
#pragma unroll
            for (int mt = 0; mt < 4; ++mt)
#pragma unroll
                for (int r = 0; r < 4; ++r)
                    atomicAdd(&rowsum[m0 + wm * 64 + mt * 16 + quad * 4 + r],
                              psum[mt][r]);
        }
    } else {
        float* C = (float*)Cv;
#pragma unroll
        for (int mt = 0; mt < 4; ++mt)
#pragma unroll
            for (int r = 0; r < 4; ++r) {
                const int row = m0 + wm * 64 + mt * 16 + quad * 4 + r;
                const float inv = 1.0f / rowsum[row];
#pragma unroll
                for (int nt = 0; nt < 4; ++nt) {
                    const int col = n0 + wn * 64 + nt * 16 + lm;
                    C[(size_t)row * ldc + col] = acc[mt][nt][r] * inv;
                }
            }
    }
}

// ---- merged projections: z=0 q, z=1 k, z=2 vT (x/y grid roles swapped) ---
__global__ __launch_bounds__(256, 4) void proj_kernel(
    const unsigned short* __restrict__ Xq, const unsigned short* __restrict__ Wq,
    unsigned short* __restrict__ qb,
    const unsigned short* __restrict__ Xk, const unsigned short* __restrict__ Wk,
    unsigned short* __restrict__ kb,
    const unsigned short* __restrict__ Wv, const unsigned short* __restrict__ Xv,
    unsigned short* __restrict__ vT) {
    const int z = blockIdx.z;
    const unsigned short* A = z == 0 ? Xq : z == 1 ? Xk : Wv;
    const unsigned short* B = z == 0 ? Wq : z == 1 ? Wk : Xv;
    unsigned short* C = z == 0 ? qb : z == 1 ? kb : vT;
    int m0, n0, ldc;
    if (z < 2) { m0 = blockIdx.x * BM; n0 = blockIdx.y * BN; ldc = 1024; }
    else       { m0 = blockIdx.y * BM; n0 = blockIdx.x * BN; ldc = 8192; }
    gemm_body<0>(A, B, C, 1024, 1024, ldc, 1024, 1.0f, nullptr, m0, n0);
}

__global__ __launch_bounds__(256, 4) void scores_kernel(
    const unsigned short* __restrict__ qb, const unsigned short* __restrict__ kb,
    unsigned short* __restrict__ Sc, float* __restrict__ rowsum) {
    const long z = blockIdx.z;
    gemm_body<1>(qb + z * 2048 * 1024, kb + z * 2048 * 1024,
                 Sc + z * 2048 * 2048, 1024, 1024, 2048, 1024,
                 1.0f / 32.0f, rowsum + z * 2048,
                 blockIdx.x * BM, blockIdx.y * BN);
}

__global__ __launch_bounds__(256, 4) void pv_kernel(
    const unsigned short* __restrict__ Sc, const unsigned short* __restrict__ vT,
    float* __restrict__ out, float* __restrict__ rowsum) {
    const long z = blockIdx.z;
    gemm_body<2>(Sc + z * 2048 * 2048, vT + z * 2048,
                 out + z * 2048 * 1024, 2048, 8192, 1024, 2048,
                 1.0f, rowsum + z * 2048,
                 blockIdx.x * BM, blockIdx.y * BN);
}

// ---------------------------------------------------------------------------
extern "C" void kernel_launch(void* const* d_in, const int* in_sizes, int n_in,
                              void* d_out, int out_size, void* d_ws, size_t ws_size,
                              hipStream_t stream) {
    const float* q_in = (const float*)d_in[0];
    const float* k_in = (const float*)d_in[1];
    const float* v_in = (const float*)d_in[2];
    const float* Qw_f = (const float*)d_in[3];
    const float* Kw_f = (const float*)d_in[4];
    const float* Vw_f = (const float*)d_in[5];
    float* out = (float*)d_out;

    const int Bb = 4, S = 2048, E = 1024;
    const size_t TOK = (size_t)Bb * S;       // 8192
    const size_t NTE = TOK * E;              // 8,388,608
    const size_t NW  = (size_t)E * E;        // 1,048,576

    unsigned short* ws = (unsigned short*)d_ws;
    unsigned short* Xq = ws;            // [8192,1024]
    unsigned short* Xk = Xq + NTE;
    unsigned short* Xv = Xk + NTE;
    unsigned short* Wq = Xv + NTE;      // [1024,1024]
    unsigned short* Wk = Wq + NW;
    unsigned short* Wv = Wk + NW;
    unsigned short* qb = Wv + NW;       // [8192,1024]
    unsigned short* kb = qb + NTE;
    unsigned short* vT = kb + NTE;      // [1024 e][8192 tok]
    unsigned short* Sc = vT + NTE;      // [4][2048][2048] exp-scores
    float* rowsum = (float*)(Sc + (size_t)Bb * S * S);  // [4][2048]

    // 1) all converts + rowsum zero, one dispatch
    {
        const long G = 3 * (long)(NTE / 4) + 3 * (long)(NW / 4) + (Bb * S / 4);
        cvt_all<<<(unsigned)(G / 256), 256, 0, stream>>>(
            q_in, k_in, v_in, Qw_f, Kw_f, Vw_f,
            Xq, Xk, Xv, Wq, Wk, Wv, rowsum);
    }

    // 2) all three projections, one dispatch (1536 blocks)
    proj_kernel<<<dim3(TOK / BM, E / BN, 3), 256, 0, stream>>>(
        Xq, Wq, qb, Xk, Wk, kb, Wv, Xv, vT);

    // 3) P = exp(q k^T / 32) + fp32 rowsums
    scores_kernel<<<dim3(S / BM, S / BN, 4), 256, 0, stream>>>(
        qb, kb, Sc, rowsum);

    // 4) out = (P @ v) / rowsum
    pv_kernel<<<dim3(S / BM, E / BN, 4), 256, 0, stream>>>(
        Sc, vT, out, rowsum);
}